// Round 10
// baseline (285.534 us; speedup 1.0000x reference)
//
#include <hip/hip_runtime.h>
#include <stdint.h>

typedef float f32x4 __attribute__((ext_vector_type(4)));

#define NROWS 8192
#define DIM   1024
#define BK    128
#define NKT   (DIM / BK)   // 8
#define MARGIN 0.3f

// fp32 [8192*1024] -> fp8 e4m3 (OCP, v_cvt_pk_fp8_f32); 16 elems/thread.
// Also zeroes the scalar output.  (verified correct R6-R9: absmax 0.0)
__global__ __launch_bounds__(256) void cvt_f32_fp8(const float* __restrict__ in,
                                                   uint8_t* __restrict__ out,
                                                   float* __restrict__ loss) {
  if (blockIdx.x == 0 && threadIdx.x == 0) loss[0] = 0.0f;
  size_t i = ((size_t)blockIdx.x * 256 + threadIdx.x) * 16;
  float4 v0 = *(const float4*)(in + i);
  float4 v1 = *(const float4*)(in + i + 4);
  float4 v2 = *(const float4*)(in + i + 8);
  float4 v3 = *(const float4*)(in + i + 12);
  int w0 = 0, w1 = 0, w2 = 0, w3 = 0;
  w0 = __builtin_amdgcn_cvt_pk_fp8_f32(v0.x, v0.y, w0, false);
  w0 = __builtin_amdgcn_cvt_pk_fp8_f32(v0.z, v0.w, w0, true);
  w1 = __builtin_amdgcn_cvt_pk_fp8_f32(v1.x, v1.y, w1, false);
  w1 = __builtin_amdgcn_cvt_pk_fp8_f32(v1.z, v1.w, w1, true);
  w2 = __builtin_amdgcn_cvt_pk_fp8_f32(v2.x, v2.y, w2, false);
  w2 = __builtin_amdgcn_cvt_pk_fp8_f32(v2.z, v2.w, w2, true);
  w3 = __builtin_amdgcn_cvt_pk_fp8_f32(v3.x, v3.y, w3, false);
  w3 = __builtin_amdgcn_cvt_pk_fp8_f32(v3.z, v3.w, w3, true);
  uint4 p; p.x = (unsigned)w0; p.y = (unsigned)w1; p.z = (unsigned)w2; p.w = (unsigned)w3;
  *(uint4*)(out + i) = p;
}

// One block = one 128x128 tile of sim = A*A^T (upper triangle, bi<=bj).
// fp8 e4m3, mfma_f32_16x16x32_fp8_fp8, XOR-swizzled LDS (R9-verified reader).
// R10: register-prefetch staging. global_load_lds forced a vmcnt(0) drain of
// the full 32KB tile at every barrier (R9: ~2566 cyc/phase vs ~310 MFMA).
// Now: per-lane global_load_dwordx4 -> VGPR issued at the TOP of compute for
// tile kt+1; ds_write_b128 g->LDS happens next iteration. The vmcnt wait
// lands after a full compute phase -> L2 latency off the barrier path.
// Per-lane ds_write also lets global reads be linear; writer applies swizzle.
__global__ __launch_bounds__(256, 3) void gram_loss(const uint8_t* __restrict__ A8,
                                                    const int* __restrict__ targets,
                                                    float* __restrict__ out) {
  __shared__ uint8_t As[128 * 128];   // 16 KB, swizzled [128][8 slots of 16B]
  __shared__ uint8_t Bs[128 * 128];   // 16 KB
  __shared__ int tRow[128];
  __shared__ int tCol[128];
  __shared__ float wsum[4];

  // linear block id -> (bi, bj) with 0 <= bi <= bj < 64  (fp32 guess + exact fixup)
  int t = blockIdx.x;
  int bi = (int)(0.5f * (129.0f - __builtin_sqrtf(129.0f * 129.0f - 8.0f * (float)t)));
  if (bi < 0) bi = 0;
  if (bi > 63) bi = 63;
  while (bi < 63 && ((bi + 1) * (129 - (bi + 1))) / 2 <= t) ++bi;
  while (bi > 0 && (bi * (129 - bi)) / 2 > t) --bi;
  int bj = bi + (t - (bi * (129 - bi)) / 2);

  const int iBase = bi * 128;
  const int jBase = bj * 128;

  const int tid  = threadIdx.x;
  const int wave = tid >> 6;
  const int lane = tid & 63;

  if (tid < 128) tRow[tid] = targets[iBase + tid];
  else           tCol[tid - 128] = targets[jBase + tid - 128];

  // staging: wave w owns rows [w*32, w*32+32) of both tiles; 4 loads each.
  // load l: row = w*32 + l*8 + (lane>>3), LINEAR col-group lane&7 (coalesced).
  // LDS slot for that 16B: swizzled col-group (lane&7) ^ (row&7), row&7 = lane>>3.
  const int lrow = lane >> 3;                 // 0..7 == row&7
  const int cgl  = lane & 7;                  // linear source col-group
  const uint8_t* gA = A8 + (size_t)(iBase + wave * 32 + lrow) * DIM + cgl * 16;
  const uint8_t* gB = A8 + (size_t)(jBase + wave * 32 + lrow) * DIM + cgl * 16;
  uint8_t* lA = &As[(wave * 32 + lrow) * 128 + ((cgl ^ lrow) * 16)];
  uint8_t* lB = &Bs[(wave * 32 + lrow) * 128 + ((cgl ^ lrow) * 16)];

  const int m0 = (wave >> 1) * 64;
  const int n0 = (wave & 1) * 64;
  const int fr = lane & 15;    // row within 16-block
  const int h  = lane >> 4;    // 0..3: k-subgroup (8 bytes) within 32B k-step
  const int r7 = fr & 7;       // swizzle key
  const int hHi = h >> 1;      // which 16B group inside the 32B k-step
  const int hLo = (h & 1) * 8; // byte offset inside the 16B group

  f32x4 acc[4][4] = {};

  // prefetch tile 0 into registers
  uint4 ga[4], gb[4];
#pragma unroll
  for (int l = 0; l < 4; ++l) {
    ga[l] = *(const uint4*)(gA + (size_t)(l * 8) * DIM);
    gb[l] = *(const uint4*)(gB + (size_t)(l * 8) * DIM);
  }

  for (int kt = 0; kt < NKT; ++kt) {
    __syncthreads();  // LDS from kt-1 fully consumed (also waits ga/gb vmcnt)
#pragma unroll
    for (int l = 0; l < 4; ++l) {
      *(uint4*)(lA + l * 8 * 128) = ga[l];
      *(uint4*)(lB + l * 8 * 128) = gb[l];
    }
    __syncthreads();  // ds_writes visible

    // issue kt+1 global loads NOW — they complete during the compute below
    if (kt + 1 < NKT) {
      const int kOff = (kt + 1) * BK;
#pragma unroll
      for (int l = 0; l < 4; ++l) {
        ga[l] = *(const uint4*)(gA + (size_t)(l * 8) * DIM + kOff);
        gb[l] = *(const uint4*)(gB + (size_t)(l * 8) * DIM + kOff);
      }
    }

    // 4 k-steps of 32; lane reads 8B of A/B per tile-row from swizzled slot
#pragma unroll
    for (int ks = 0; ks < 4; ++ks) {
      const int colOff = (((ks * 2 + hHi) ^ r7) * 16) + hLo;
      long af[4], bf[4];
#pragma unroll
      for (int mi = 0; mi < 4; ++mi)
        af[mi] = *(const long*)&As[(m0 + mi * 16 + fr) * 128 + colOff];
#pragma unroll
      for (int ni = 0; ni < 4; ++ni)
        bf[ni] = *(const long*)&Bs[(n0 + ni * 16 + fr) * 128 + colOff];
#pragma unroll
      for (int mi = 0; mi < 4; ++mi)
#pragma unroll
        for (int ni = 0; ni < 4; ++ni)
          acc[mi][ni] = __builtin_amdgcn_mfma_f32_16x16x32_fp8_fp8(
              af[mi], bf[ni], acc[mi][ni], 0, 0, 0);
    }
  }

  // epilogue: C/D layout col = lane&15, row = (lane>>4)*4 + reg (dtype-indep)
  const int col = lane & 15;
  const int rquad = (lane >> 4) * 4;
  float lsum = 0.0f;
#pragma unroll
  for (int ni = 0; ni < 4; ++ni) {
    const int tj = tCol[n0 + ni * 16 + col];
#pragma unroll
    for (int mi = 0; mi < 4; ++mi) {
#pragma unroll
      for (int r = 0; r < 4; ++r) {
        float s = acc[mi][ni][r];
        int ti = tRow[m0 + mi * 16 + rquad + r];
        lsum += (ti == tj) ? (s < 1.0f ? 1.0f - s : 0.0f)
                           : (s > MARGIN ? s : 0.0f);
      }
    }
  }
  if (bi != bj) lsum *= 2.0f;  // symmetric half counted twice

#pragma unroll
  for (int off = 32; off > 0; off >>= 1) lsum += __shfl_down(lsum, off, 64);
  if (lane == 0) wsum[wave] = lsum;
  __syncthreads();
  if (tid == 0)
    atomicAdd(out, (wsum[0] + wsum[1] + wsum[2] + wsum[3]) * (1.0f / (float)NROWS));
}

extern "C" void kernel_launch(void* const* d_in, const int* in_sizes, int n_in,
                              void* d_out, int out_size, void* d_ws, size_t ws_size,
                              hipStream_t stream) {
  const float* x = (const float*)d_in[0];
  const int* targets = (const int*)d_in[1];
  float* out = (float*)d_out;
  uint8_t* x8 = (uint8_t*)d_ws;  // 8192*1024 = 8 MiB scratch

  cvt_f32_fp8<<<2048, 256, 0, stream>>>(x, x8, out);   // 8388608 = 2048*256*16
  gram_loss<<<2080, 256, 0, stream>>>(x8, targets, out);  // 64*65/2 upper-tri blocks
}

// Round 11
// 161.057 us; speedup vs baseline: 1.7729x; 1.7729x over previous
//
#include <hip/hip_runtime.h>
#include <stdint.h>

typedef float f32x4 __attribute__((ext_vector_type(4)));

#define NROWS 8192
#define DIM   1024
#define BK    128
#define NKT   (DIM / BK)   // 8
#define MARGIN 0.3f

// fp32 [8192*1024] -> fp8 e4m3 (OCP, v_cvt_pk_fp8_f32); 16 elems/thread.
// Also zeroes the scalar output.  (verified correct R6-R10: absmax 0.0)
__global__ __launch_bounds__(256) void cvt_f32_fp8(const float* __restrict__ in,
                                                   uint8_t* __restrict__ out,
                                                   float* __restrict__ loss) {
  if (blockIdx.x == 0 && threadIdx.x == 0) loss[0] = 0.0f;
  size_t i = ((size_t)blockIdx.x * 256 + threadIdx.x) * 16;
  float4 v0 = *(const float4*)(in + i);
  float4 v1 = *(const float4*)(in + i + 4);
  float4 v2 = *(const float4*)(in + i + 8);
  float4 v3 = *(const float4*)(in + i + 12);
  int w0 = 0, w1 = 0, w2 = 0, w3 = 0;
  w0 = __builtin_amdgcn_cvt_pk_fp8_f32(v0.x, v0.y, w0, false);
  w0 = __builtin_amdgcn_cvt_pk_fp8_f32(v0.z, v0.w, w0, true);
  w1 = __builtin_amdgcn_cvt_pk_fp8_f32(v1.x, v1.y, w1, false);
  w1 = __builtin_amdgcn_cvt_pk_fp8_f32(v1.z, v1.w, w1, true);
  w2 = __builtin_amdgcn_cvt_pk_fp8_f32(v2.x, v2.y, w2, false);
  w2 = __builtin_amdgcn_cvt_pk_fp8_f32(v2.z, v2.w, w2, true);
  w3 = __builtin_amdgcn_cvt_pk_fp8_f32(v3.x, v3.y, w3, false);
  w3 = __builtin_amdgcn_cvt_pk_fp8_f32(v3.z, v3.w, w3, true);
  uint4 p; p.x = (unsigned)w0; p.y = (unsigned)w1; p.z = (unsigned)w2; p.w = (unsigned)w3;
  *(uint4*)(out + i) = p;
}

// One block = one 128x128 tile of sim = A*A^T (upper triangle, bi<=bj).
// fp8 e4m3, mfma_f32_16x16x32_fp8_fp8, XOR-swizzled LDS (R9-verified reader).
// Register-prefetch pipeline (R10 concept), R11 spill fixes:
//  - NO min-waves bound: R10's (256,3) ~170-reg cap spilled the 128B/thread
//    prefetch set -> 525 MB scratch writes (986 B/thread = 8kt x 128B).
//  - prefetch in 8 NAMED uint4s (no array aggregate to demote).
//  - unconditional wrapped prefetch offset ((kt+1)&7): no conditional
//    assignment fragmenting the live range.
__global__ __launch_bounds__(256) void gram_loss(const uint8_t* __restrict__ A8,
                                                 const int* __restrict__ targets,
                                                 float* __restrict__ out) {
  __shared__ uint8_t As[128 * 128];   // 16 KB, swizzled [128][8 slots of 16B]
  __shared__ uint8_t Bs[128 * 128];   // 16 KB
  __shared__ int tRow[128];
  __shared__ int tCol[128];
  __shared__ float wsum[4];

  // linear block id -> (bi, bj) with 0 <= bi <= bj < 64  (fp32 guess + exact fixup)
  int t = blockIdx.x;
  int bi = (int)(0.5f * (129.0f - __builtin_sqrtf(129.0f * 129.0f - 8.0f * (float)t)));
  if (bi < 0) bi = 0;
  if (bi > 63) bi = 63;
  while (bi < 63 && ((bi + 1) * (129 - (bi + 1))) / 2 <= t) ++bi;
  while (bi > 0 && (bi * (129 - bi)) / 2 > t) --bi;
  int bj = bi + (t - (bi * (129 - bi)) / 2);

  const int iBase = bi * 128;
  const int jBase = bj * 128;

  const int tid  = threadIdx.x;
  const int wave = tid >> 6;
  const int lane = tid & 63;

  if (tid < 128) tRow[tid] = targets[iBase + tid];
  else           tCol[tid - 128] = targets[jBase + tid - 128];

  // staging: wave w owns rows [w*32, w*32+32) of both tiles; 4 loads each.
  // load l: row = w*32 + l*8 + (lane>>3), LINEAR col-group lane&7 (coalesced).
  // LDS slot for that 16B: swizzled col-group (lane&7) ^ (row&7), row&7 = lane>>3.
  const int lrow = lane >> 3;                 // 0..7 == row&7
  const int cgl  = lane & 7;                  // linear source col-group
  const uint8_t* gA = A8 + (size_t)(iBase + wave * 32 + lrow) * DIM + cgl * 16;
  const uint8_t* gB = A8 + (size_t)(jBase + wave * 32 + lrow) * DIM + cgl * 16;
  uint8_t* lA = &As[(wave * 32 + lrow) * 128 + ((cgl ^ lrow) * 16)];
  uint8_t* lB = &Bs[(wave * 32 + lrow) * 128 + ((cgl ^ lrow) * 16)];

  const int m0 = (wave >> 1) * 64;
  const int n0 = (wave & 1) * 64;
  const int fr = lane & 15;    // row within 16-block
  const int h  = lane >> 4;    // 0..3: k-subgroup (8 bytes) within 32B k-step
  const int r7 = fr & 7;       // swizzle key
  const int hHi = h >> 1;      // which 16B group inside the 32B k-step
  const int hLo = (h & 1) * 8; // byte offset inside the 16B group

  f32x4 acc[4][4] = {};

  // prefetch tile 0 into named registers (8 x uint4 = 32 VGPRs)
  uint4 ga0 = *(const uint4*)(gA + (size_t)0 * DIM);
  uint4 ga1 = *(const uint4*)(gA + (size_t)8 * DIM);
  uint4 ga2 = *(const uint4*)(gA + (size_t)16 * DIM);
  uint4 ga3 = *(const uint4*)(gA + (size_t)24 * DIM);
  uint4 gb0 = *(const uint4*)(gB + (size_t)0 * DIM);
  uint4 gb1 = *(const uint4*)(gB + (size_t)8 * DIM);
  uint4 gb2 = *(const uint4*)(gB + (size_t)16 * DIM);
  uint4 gb3 = *(const uint4*)(gB + (size_t)24 * DIM);

  for (int kt = 0; kt < NKT; ++kt) {
    __syncthreads();  // LDS from kt-1 fully consumed (also waits ga/gb vmcnt)
    *(uint4*)(lA + 0 * 1024) = ga0;
    *(uint4*)(lA + 1 * 1024) = ga1;
    *(uint4*)(lA + 2 * 1024) = ga2;
    *(uint4*)(lA + 3 * 1024) = ga3;
    *(uint4*)(lB + 0 * 1024) = gb0;
    *(uint4*)(lB + 1 * 1024) = gb1;
    *(uint4*)(lB + 2 * 1024) = gb2;
    *(uint4*)(lB + 3 * 1024) = gb3;
    __syncthreads();  // ds_writes visible

    // issue kt+1 loads NOW (wrapped offset keeps them unconditional); they
    // complete during the compute below — vmcnt wait is at the NEXT barrier
    const int kOff = ((kt + 1) & 7) * BK;
    ga0 = *(const uint4*)(gA + (size_t)0 * DIM + kOff);
    ga1 = *(const uint4*)(gA + (size_t)8 * DIM + kOff);
    ga2 = *(const uint4*)(gA + (size_t)16 * DIM + kOff);
    ga3 = *(const uint4*)(gA + (size_t)24 * DIM + kOff);
    gb0 = *(const uint4*)(gB + (size_t)0 * DIM + kOff);
    gb1 = *(const uint4*)(gB + (size_t)8 * DIM + kOff);
    gb2 = *(const uint4*)(gB + (size_t)16 * DIM + kOff);
    gb3 = *(const uint4*)(gB + (size_t)24 * DIM + kOff);

    // 4 k-steps of 32; lane reads 8B of A/B per tile-row from swizzled slot
#pragma unroll
    for (int ks = 0; ks < 4; ++ks) {
      const int colOff = (((ks * 2 + hHi) ^ r7) * 16) + hLo;
      long af[4], bf[4];
#pragma unroll
      for (int mi = 0; mi < 4; ++mi)
        af[mi] = *(const long*)&As[(m0 + mi * 16 + fr) * 128 + colOff];
#pragma unroll
      for (int ni = 0; ni < 4; ++ni)
        bf[ni] = *(const long*)&Bs[(n0 + ni * 16 + fr) * 128 + colOff];
#pragma unroll
      for (int mi = 0; mi < 4; ++mi)
#pragma unroll
        for (int ni = 0; ni < 4; ++ni)
          acc[mi][ni] = __builtin_amdgcn_mfma_f32_16x16x32_fp8_fp8(
              af[mi], bf[ni], acc[mi][ni], 0, 0, 0);
    }
  }

  // epilogue: C/D layout col = lane&15, row = (lane>>4)*4 + reg (dtype-indep)
  const int col = lane & 15;
  const int rquad = (lane >> 4) * 4;
  float lsum = 0.0f;
#pragma unroll
  for (int ni = 0; ni < 4; ++ni) {
    const int tj = tCol[n0 + ni * 16 + col];
#pragma unroll
    for (int mi = 0; mi < 4; ++mi) {
#pragma unroll
      for (int r = 0; r < 4; ++r) {
        float s = acc[mi][ni][r];
        int ti = tRow[m0 + mi * 16 + rquad + r];
        lsum += (ti == tj) ? (s < 1.0f ? 1.0f - s : 0.0f)
                           : (s > MARGIN ? s : 0.0f);
      }
    }
  }
  if (bi != bj) lsum *= 2.0f;  // symmetric half counted twice

#pragma unroll
  for (int off = 32; off > 0; off >>= 1) lsum += __shfl_down(lsum, off, 64);
  if (lane == 0) wsum[wave] = lsum;
  __syncthreads();
  if (tid == 0)
    atomicAdd(out, (wsum[0] + wsum[1] + wsum[2] + wsum[3]) * (1.0f / (float)NROWS));
}

extern "C" void kernel_launch(void* const* d_in, const int* in_sizes, int n_in,
                              void* d_out, int out_size, void* d_ws, size_t ws_size,
                              hipStream_t stream) {
  const float* x = (const float*)d_in[0];
  const int* targets = (const int*)d_in[1];
  float* out = (float*)d_out;
  uint8_t* x8 = (uint8_t*)d_ws;  // 8192*1024 = 8 MiB scratch

  cvt_f32_fp8<<<2048, 256, 0, stream>>>(x, x8, out);   // 8388608 = 2048*256*16
  gram_loss<<<2080, 256, 0, stream>>>(x8, targets, out);  // 64*65/2 upper-tri blocks
}